// Round 1
// baseline (75.635 us; speedup 1.0000x reference)
//
#include <hip/hip_runtime.h>

#define N_PIX 4096
#define N_CH 256
#define KSEL 16
#define TCAP 256

__device__ __forceinline__ unsigned f2key(float f) {
  unsigned u = __float_as_uint(f);
  return u ^ ((unsigned)((int)u >> 31) | 0x80000000u);
}
__device__ __forceinline__ float key2f(unsigned k) {
  unsigned u = (k & 0x80000000u) ? (k ^ 0x80000000u) : ~k;
  return __uint_as_float(u);
}

// feat [B, C, N] -> feat_t [B, N, C], 32x32 LDS tile transpose
__global__ void transpose_feat_kernel(const float* __restrict__ feat,
                                      float* __restrict__ feat_t) {
  __shared__ float tile[32][33];
  const int b = blockIdx.z;
  const int n0 = blockIdx.x * 32;
  const int c0 = blockIdx.y * 32;
  const int tx = threadIdx.x, ty = threadIdx.y;
  const float* src = feat + (size_t)b * N_CH * N_PIX;
  float* dst = feat_t + (size_t)b * N_PIX * N_CH;
#pragma unroll
  for (int j = 0; j < 32; j += 8)
    tile[ty + j][tx] = src[(size_t)(c0 + ty + j) * N_PIX + n0 + tx];
  __syncthreads();
#pragma unroll
  for (int j = 0; j < 32; j += 8)
    dst[(size_t)(n0 + ty + j) * N_CH + c0 + tx] = tile[tx][ty + j];
}

// One block per (b, i) row: radix-select top-16 of 4096, softmax, gather-sum.
template <bool FT>
__global__ __launch_bounds__(256) void topk_assemble_kernel(
    const float* __restrict__ aff, const float* __restrict__ feat,
    float* __restrict__ out) {
  __shared__ unsigned hist[256];
  __shared__ unsigned tie_idx[TCAP];
  __shared__ unsigned sel_key[KSEL];
  __shared__ unsigned sel_idx[KSEL];
  __shared__ float s_w[KSEL];
  __shared__ unsigned s_bin, s_gt, nsel, ntie;

  const int tid = threadIdx.x;
  const int row = blockIdx.x;
  const int b = row >> 12;           // N_PIX = 4096
  const int i = row & (N_PIX - 1);

  // coalesced row load; sortable keys kept in registers (16 per thread)
  const float4* arow = (const float4*)(aff + (size_t)row * N_PIX);
  unsigned key[16];
#pragma unroll
  for (int q = 0; q < 4; ++q) {
    float4 v = arow[q * 256 + tid];
    key[q * 4 + 0] = f2key(v.x);
    key[q * 4 + 1] = f2key(v.y);
    key[q * 4 + 2] = f2key(v.z);
    key[q * 4 + 3] = f2key(v.w);
  }

  hist[tid] = 0;
  if (tid == 0) { nsel = 0; ntie = 0; }
  __syncthreads();

  unsigned prefix = 0;
  unsigned remaining = KSEL;
  int shift = 24;
  bool exact = false;

  for (int level = 0; level < 4; ++level) {
    shift = 24 - 8 * level;
    // histogram of elements whose higher bits match the current prefix
#pragma unroll
    for (int e = 0; e < 16; ++e) {
      unsigned k = key[e];
      bool match = (level == 0) || (((k >> shift) >> 8) == prefix);
      if (match) atomicAdd(&hist[(k >> shift) & 0xFFu], 1u);
    }
    __syncthreads();
    // single-wave suffix scan over 256 bins (4 bins/lane) to find threshold bin
    if (tid < 64) {
      const int l = tid;
      unsigned h0 = hist[4 * l + 0], h1 = hist[4 * l + 1];
      unsigned h2 = hist[4 * l + 2], h3 = hist[4 * l + 3];
      unsigned s = h0 + h1 + h2 + h3;
      unsigned suf = s;
#pragma unroll
      for (int off = 1; off < 64; off <<= 1) {
        unsigned o = __shfl_down(suf, off, 64);
        if (l + off < 64) suf += o;
      }
      unsigned g3 = suf - s;      // count in bins > 4l+3
      unsigned g2 = g3 + h3;
      unsigned g1 = g2 + h2;
      unsigned g0 = g1 + h1;
      if (g0 < remaining && remaining <= g0 + h0) { s_bin = 4u * l + 0; s_gt = g0; }
      if (g1 < remaining && remaining <= g1 + h1) { s_bin = 4u * l + 1; s_gt = g1; }
      if (g2 < remaining && remaining <= g2 + h2) { s_bin = 4u * l + 2; s_gt = g2; }
      if (g3 < remaining && remaining <= g3 + h3) { s_bin = 4u * l + 3; s_gt = g3; }
    }
    __syncthreads();
    unsigned bin = s_bin;
    unsigned hbin = hist[bin];
    remaining -= s_gt;
    prefix = (prefix << 8) | bin;
    exact = (hbin == remaining);
    __syncthreads();
    hist[tid] = 0;
    __syncthreads();
    if (exact) break;
  }

  // collect the selected set
#pragma unroll
  for (int e = 0; e < 16; ++e) {
    unsigned k = key[e];
    unsigned j = (unsigned)((e >> 2) * 1024 + tid * 4 + (e & 3));
    if (exact) {
      if ((k >> shift) >= prefix) {
        unsigned p = atomicAdd(&nsel, 1u);
        sel_key[p] = k; sel_idx[p] = j;
      }
    } else {
      if (k > prefix) {
        unsigned p = atomicAdd(&nsel, 1u);
        sel_key[p] = k; sel_idx[p] = j;
      } else if (k == prefix) {
        unsigned p = atomicAdd(&ntie, 1u);
        if (p < TCAP) tie_idx[p] = j;
      }
    }
  }
  __syncthreads();
  // exact-key ties at the threshold: take lowest indices (top_k semantics)
  if (!exact && tid == 0) {
    unsigned m = ntie < TCAP ? ntie : TCAP;
    unsigned base = nsel;
    for (unsigned r = 0; r < remaining; ++r) {
      unsigned bi = 0xFFFFFFFFu, bp = 0;
      for (unsigned t = 0; t < m; ++t)
        if (tie_idx[t] < bi) { bi = tie_idx[t]; bp = t; }
      tie_idx[bp] = 0xFFFFFFFFu;
      sel_key[base + r] = prefix;
      sel_idx[base + r] = bi;
    }
  }
  __syncthreads();

  // softmax over the 16 selected values (order-invariant)
  if (tid < 16) {
    float v = key2f(sel_key[tid]);
    float vm = v;
#pragma unroll
    for (int m = 1; m < 16; m <<= 1) vm = fmaxf(vm, __shfl_xor(vm, m, 64));
    float e = __expf(v - vm);
    float ssum = e;
#pragma unroll
    for (int m = 1; m < 16; m <<= 1) ssum += __shfl_xor(ssum, m, 64);
    s_w[tid] = e / ssum;
  }
  __syncthreads();

  // weighted gather-sum: thread = channel
  float acc = 0.f;
#pragma unroll
  for (int k = 0; k < 16; ++k) {
    float w = s_w[k];
    unsigned j = sel_idx[k];
    float f;
    if (FT)
      f = feat[((size_t)b * N_PIX + j) * N_CH + tid];   // [B,N,C] coalesced
    else
      f = feat[((size_t)b * N_CH + tid) * N_PIX + j];   // [B,C,N] fallback
    acc = fmaf(w, f, acc);
  }
  out[((size_t)(b * N_CH + tid)) * N_PIX + i] = acc;
}

extern "C" void kernel_launch(void* const* d_in, const int* in_sizes, int n_in,
                              void* d_out, int out_size, void* d_ws, size_t ws_size,
                              hipStream_t stream) {
  const float* aff = (const float*)d_in[0];
  const float* feat = (const float*)d_in[1];
  float* out = (float*)d_out;
  const size_t feat_t_bytes = (size_t)2 * N_PIX * N_CH * sizeof(float);
  if (ws_size >= feat_t_bytes) {
    float* feat_t = (float*)d_ws;
    dim3 tb(32, 8, 1);
    dim3 tg(N_PIX / 32, N_CH / 32, 2);
    transpose_feat_kernel<<<tg, tb, 0, stream>>>(feat, feat_t);
    topk_assemble_kernel<true><<<2 * N_PIX, 256, 0, stream>>>(aff, feat_t, out);
  } else {
    topk_assemble_kernel<false><<<2 * N_PIX, 256, 0, stream>>>(aff, feat, out);
  }
}

// Round 2
// 73.088 us; speedup vs baseline: 1.0348x; 1.0348x over previous
//
#include <hip/hip_runtime.h>

#define N_PIX 4096
#define N_CH 256
#define KSEL 16

__device__ __forceinline__ unsigned f2key(float f) {
  unsigned u = __float_as_uint(f);
  return u ^ ((unsigned)((int)u >> 31) | 0x80000000u);
}
__device__ __forceinline__ float key2f(unsigned k) {
  unsigned u = (k & 0x80000000u) ? (k ^ 0x80000000u) : ~k;
  return __uint_as_float(u);
}
__device__ __forceinline__ unsigned umaxu(unsigned a, unsigned b) { return a > b ? a : b; }

// feat [B, C, N] -> feat_t [B, N, C], 32x32 LDS tile transpose
__global__ void transpose_feat_kernel(const float* __restrict__ feat,
                                      float* __restrict__ feat_t) {
  __shared__ float tile[32][33];
  const int b = blockIdx.z;
  const int n0 = blockIdx.x * 32;
  const int c0 = blockIdx.y * 32;
  const int tx = threadIdx.x, ty = threadIdx.y;
  const float* src = feat + (size_t)b * N_CH * N_PIX;
  float* dst = feat_t + (size_t)b * N_PIX * N_CH;
#pragma unroll
  for (int j = 0; j < 32; j += 8)
    tile[ty + j][tx] = src[(size_t)(c0 + ty + j) * N_PIX + n0 + tx];
  __syncthreads();
#pragma unroll
  for (int j = 0; j < 32; j += 8)
    dst[(size_t)(n0 + ty + j) * N_CH + c0 + tx] = tile[tx][ty + j];
}

// One WAVE per row. Register radix-select via ballot counts (no LDS atomics,
// no per-level barriers). Block = 4 waves = 4 consecutive rows; output staged
// in LDS and written as float4 along i (XCD-swizzled so neighboring blocks
// share an L2 and write-combine full lines).
#define EMIT(KK, J)                                            \
  {                                                            \
    float v_ = key2f(KK);                                      \
    float ev_ = __expf(v_ - vmax);                             \
    ssum += ev_;                                               \
    if (lane == 0) { s_j[w][nw] = (J); s_e[w][nw] = ev_; }     \
    ++nw;                                                      \
  }

template <bool FT>
__global__ __launch_bounds__(256) void topk_row_kernel(
    const float* __restrict__ aff, const float* __restrict__ feat,
    float* __restrict__ out) {
  __shared__ unsigned s_j[4][KSEL];
  __shared__ float s_e[4][KSEL];
  __shared__ float s_out[4][N_CH];

  const int tid = threadIdx.x;
  const int lane = tid & 63;
  const int w = tid >> 6;

  // XCD swizzle: consecutive row-groups stay on one XCD (write-combining + L2 reuse)
  const int rg = (blockIdx.x & 7) * ((int)gridDim.x >> 3) + ((int)blockIdx.x >> 3);
  const int row = rg * 4 + w;
  const int b = row >> 12;

  // ---- load row (coalesced float4), build sortable keys in registers ----
  const float4* arow = (const float4*)(aff + (size_t)row * N_PIX);
  unsigned key[64];
  unsigned kmax = 0;
#pragma unroll
  for (int q = 0; q < 16; ++q) {
    float4 v = arow[q * 64 + lane];
    unsigned k0 = f2key(v.x), k1 = f2key(v.y), k2 = f2key(v.z), k3 = f2key(v.w);
    key[q * 4 + 0] = k0; key[q * 4 + 1] = k1;
    key[q * 4 + 2] = k2; key[q * 4 + 3] = k3;
    kmax = umaxu(kmax, umaxu(umaxu(k0, k1), umaxu(k2, k3)));
  }
#pragma unroll
  for (int off = 32; off >= 1; off >>= 1)
    kmax = umaxu(kmax, (unsigned)__shfl_xor((int)kmax, off, 64));
  const float vmax = key2f(kmax);

  // ---- radix-select the 16th-largest key (ballot counting, MSB->LSB) ----
  unsigned prefix = 0, need = KSEL;
  int startbit = 31;
  {
    // jumpstart: if >=16 keys share the max's top 9 bits (sign+exponent),
    // the whole top-16 lives in that bucket -> skip bits 31..23.
    const unsigned p9 = kmax >> 23;
    unsigned c9 = 0;
#pragma unroll
    for (int e = 0; e < 64; ++e)
      c9 += (unsigned)__popcll(__ballot((key[e] >> 23) == p9));
    if (c9 >= KSEL) { prefix = p9; startbit = 22; }
  }
  bool early = false;
  int bit = startbit;
  for (; bit >= 0; --bit) {
    const unsigned want = (prefix << 1) | 1u;
    unsigned cnt = 0;
#pragma unroll
    for (int e = 0; e < 64; ++e)
      cnt += (unsigned)__popcll(__ballot((key[e] >> bit) == want));
    if (cnt >= need) {
      prefix = want;
      if (cnt == need) { early = true; break; }
    } else {
      need -= cnt;
      prefix <<= 1;
    }
  }

  // ---- enumerate winners; accumulate softmax denominator; stash (j, e^v) ----
  float ssum = 0.f;
  int nw = 0;
  if (early) {
    const unsigned thr = prefix << bit;  // exactly KSEL keys >= thr, no ties
#pragma unroll
    for (int e = 0; e < 64; ++e) {
      unsigned long long m = __ballot(key[e] >= thr);
      while (m) {
        int l = (int)__builtin_ctzll(m);
        m &= m - 1;
        unsigned kk = (unsigned)__shfl((int)key[e], l, 64);
        EMIT(kk, (unsigned)((e >> 2) * 256 + l * 4 + (e & 3)));
      }
    }
  } else {
    const unsigned T = prefix;  // exact threshold key; take key>T plus lowest-index ties
#pragma unroll
    for (int e = 0; e < 64; ++e) {
      unsigned long long m = __ballot(key[e] > T);
      while (m) {
        int l = (int)__builtin_ctzll(m);
        m &= m - 1;
        unsigned kk = (unsigned)__shfl((int)key[e], l, 64);
        EMIT(kk, (unsigned)((e >> 2) * 256 + l * 4 + (e & 3)));
      }
    }
#pragma unroll
    for (int q = 0; q < 16; ++q) {
      if (need) {
        unsigned long long mc0 = __ballot(key[q * 4 + 0] == T);
        unsigned long long mc1 = __ballot(key[q * 4 + 1] == T);
        unsigned long long mc2 = __ballot(key[q * 4 + 2] == T);
        unsigned long long mc3 = __ballot(key[q * 4 + 3] == T);
        unsigned long long any = mc0 | mc1 | mc2 | mc3;
        while (any && need) {
          int l = (int)__builtin_ctzll(any);
          any &= any - 1;
          if (need && ((mc0 >> l) & 1)) { EMIT(T, (unsigned)(q * 256 + l * 4 + 0)); --need; }
          if (need && ((mc1 >> l) & 1)) { EMIT(T, (unsigned)(q * 256 + l * 4 + 1)); --need; }
          if (need && ((mc2 >> l) & 1)) { EMIT(T, (unsigned)(q * 256 + l * 4 + 2)); --need; }
          if (need && ((mc3 >> l) & 1)) { EMIT(T, (unsigned)(q * 256 + l * 4 + 3)); --need; }
        }
      }
    }
  }

  __syncthreads();  // publish s_j/s_e (and order vs. s_out staging below)

  // ---- weighted gather-sum: lane owns 4 channels, 16 independent float4 loads ----
  const float rs = 1.0f / ssum;
  float ax = 0.f, ay = 0.f, az = 0.f, aw = 0.f;
  if (FT) {
    const float* fb = feat + (size_t)b * N_PIX * N_CH + lane * 4;
#pragma unroll
    for (int k = 0; k < KSEL; ++k) {
      const unsigned j = s_j[w][k];
      const float ev = s_e[w][k];
      const float4 f = *(const float4*)(fb + (size_t)j * N_CH);
      ax += ev * f.x; ay += ev * f.y; az += ev * f.z; aw += ev * f.w;
    }
  } else {
    const float* fb = feat + (size_t)b * N_CH * N_PIX;
    const int c0 = lane * 4;
#pragma unroll
    for (int k = 0; k < KSEL; ++k) {
      const unsigned j = s_j[w][k];
      const float ev = s_e[w][k];
      ax += ev * fb[(size_t)(c0 + 0) * N_PIX + j];
      ay += ev * fb[(size_t)(c0 + 1) * N_PIX + j];
      az += ev * fb[(size_t)(c0 + 2) * N_PIX + j];
      aw += ev * fb[(size_t)(c0 + 3) * N_PIX + j];
    }
  }
  float4 accv; accv.x = ax * rs; accv.y = ay * rs; accv.z = az * rs; accv.w = aw * rs;
  *(float4*)&s_out[w][lane * 4] = accv;

  __syncthreads();

  // ---- write out[b, c, i0..i0+3] as one float4 per channel ----
  {
    const int c = tid;
    const int bb = rg >> 10;
    const int i0 = (rg & 1023) * 4;
    float4 o;
    o.x = s_out[0][c]; o.y = s_out[1][c]; o.z = s_out[2][c]; o.w = s_out[3][c];
    *(float4*)(out + ((size_t)(bb * N_CH + c)) * N_PIX + i0) = o;
  }
}

extern "C" void kernel_launch(void* const* d_in, const int* in_sizes, int n_in,
                              void* d_out, int out_size, void* d_ws, size_t ws_size,
                              hipStream_t stream) {
  const float* aff = (const float*)d_in[0];
  const float* feat = (const float*)d_in[1];
  float* out = (float*)d_out;
  const size_t feat_t_bytes = (size_t)2 * N_PIX * N_CH * sizeof(float);
  if (ws_size >= feat_t_bytes) {
    float* feat_t = (float*)d_ws;
    dim3 tb(32, 8, 1);
    dim3 tg(N_PIX / 32, N_CH / 32, 2);
    transpose_feat_kernel<<<tg, tb, 0, stream>>>(feat, feat_t);
    topk_row_kernel<true><<<2048, 256, 0, stream>>>(aff, feat_t, out);
  } else {
    topk_row_kernel<false><<<2048, 256, 0, stream>>>(aff, feat, out);
  }
}